// Round 6
// baseline (180.725 us; speedup 1.0000x reference)
//
#include <hip/hip_runtime.h>
#include <hip/hip_bf16.h>

// AngleProtoLoss: loss = -mean_n logsoftmax(clip(cos(last_n,cent_k),1e-6)*w+b)[n,n]
// Identity: loss_n = ln2*(log2(sum_k 2^{z_nk}) - z_nn), z = clamp(cos*w*log2e); b cancels.
// k1: centroids+norms -> unit cent (bf16), w*log2e-prescaled unit last (bf16), fp32 z_nn.
// k2: grid (32,16) x 512 threads (8 waves = 4 row-groups x 2 col-halves). Wave owns
//     64 rows (a[4][4], compiles ~64 VGPR per R3) but only HALF the B-slab per iter
//     (8 ds_read_b128 vs 16) -> block LDS-read traffic halved. One-sided clamp
//     (wave-uniform sign branch). LDS image & XOR chunk swizzle identical to R0.
// PROBE (this round only): k2 launched TWICE, second into scratch zsum2 (k3 ignores).
//     T6 - T7(next round, duplicate removed) = k2's true duration -- the per-kernel
//     timing rocprof's top-5 (all ~44us harness fills) cannot give us.
// k3: single block: loss = ln2/N * sum_n (log2(S_n) - z_nn).
// R1 post-mortem: per-block __threadfence()+ticket fusion serializes k2 to 73us.
// R3 post-mortem: 1024 blocks thrashes XCD L2. Keep 512 blocks.

typedef __attribute__((ext_vector_type(8))) short short8;
typedef __attribute__((ext_vector_type(4))) float f32x4;

#define NSPK 8192
#define DEMB 128
#define MUTT 10
#define LOG2E 1.44269504088896340736f
#define LN2   0.69314718055994530942f

// workspace floats: [0,8192)=zdiag, [8192,16384)=zsum; bytes: lastb/centb; zsum2 after.
#define WS_ZDIAG 0
#define WS_ZSUM  8192
#define WS_LASTB 65536      // byte offset, 2 MB
#define WS_CENTB 2162688    // byte offset, 2 MB
#define WS_ZSUM2 1064960    // float index (byte 4259840, after centb) -- probe target

__global__ __launch_bounds__(256) void k1_prep(const float* __restrict__ x,
                                               const float* __restrict__ wp,
                                               float* __restrict__ W,
                                               __hip_bfloat16* __restrict__ lastb,
                                               __hip_bfloat16* __restrict__ centb) {
    const int wv = threadIdx.x >> 6;
    const int l  = threadIdx.x & 63;
    const int n  = blockIdx.x * 4 + wv;           // one wave per speaker
    if (blockIdx.x < 32) W[WS_ZSUM + blockIdx.x * 256 + threadIdx.x] = 0.f;
    if (blockIdx.x >= 32 && blockIdx.x < 64)
        W[WS_ZSUM2 + (blockIdx.x - 32) * 256 + threadIdx.x] = 0.f;

    // flat 1280 floats per speaker; lane l, step i -> float4 at 64*i + l.
    // lanes 0..31: m = 2i ; lanes 32..63: m = 2i+1
    const float4* xr = (const float4*)(x + (size_t)n * (MUTT * DEMB)) + l;
    float4 v[5];
#pragma unroll
    for (int i = 0; i < 5; ++i) v[i] = xr[i * 64];

    float4 cs;
    cs.x = ((v[0].x + v[1].x) + (v[2].x + v[3].x)) + v[4].x;
    cs.y = ((v[0].y + v[1].y) + (v[2].y + v[3].y)) + v[4].y;
    cs.z = ((v[0].z + v[1].z) + (v[2].z + v[3].z)) + v[4].z;
    cs.w = ((v[0].w + v[1].w) + (v[2].w + v[3].w)) + v[4].w;
    cs.x += __shfl_xor(cs.x, 32);
    cs.y += __shfl_xor(cs.y, 32);
    cs.z += __shfl_xor(cs.z, 32);
    cs.w += __shfl_xor(cs.w, 32);
    float4 cent;
    cent.x = cs.x * 0.1f; cent.y = cs.y * 0.1f; cent.z = cs.z * 0.1f; cent.w = cs.w * 0.1f;

    // last row (m=9) lives in v[4] of lanes >= 32; mirror into lanes < 32
    float4 lv = v[4];
    {
        const float tx = __shfl_xor(lv.x, 32);
        const float ty = __shfl_xor(lv.y, 32);
        const float tz = __shfl_xor(lv.z, 32);
        const float tw = __shfl_xor(lv.w, 32);
        if (l < 32) { lv.x = tx; lv.y = ty; lv.z = tz; lv.w = tw; }
    }

    float sl = lv.x * lv.x + lv.y * lv.y + lv.z * lv.z + lv.w * lv.w;
    float sc = cent.x * cent.x + cent.y * cent.y + cent.z * cent.z + cent.w * cent.w;
    float dp = lv.x * cent.x + lv.y * cent.y + lv.z * cent.z + lv.w * cent.w;
#pragma unroll
    for (int off = 1; off < 32; off <<= 1) {
        sl += __shfl_xor(sl, off);
        sc += __shfl_xor(sc, off);
        dp += __shfl_xor(dp, off);
    }
    const float il = rsqrtf(sl), ic = rsqrtf(sc);
    const float scale = wp[0] * LOG2E;
    const float as = il * scale;                  // prescale last by w*log2e

    const float  f  = (l < 32) ? as : ic;
    const float4 s4 = (l < 32) ? lv : cent;
    __hip_bfloat16* bp = ((l < 32) ? lastb : centb) + (size_t)n * DEMB + 4 * (l & 31);
    union { __hip_bfloat162 h[2]; uint2 u; } pk;
    pk.h[0].x = __float2bfloat16(s4.x * f);
    pk.h[0].y = __float2bfloat16(s4.y * f);
    pk.h[1].x = __float2bfloat16(s4.z * f);
    pk.h[1].y = __float2bfloat16(s4.w * f);
    *(uint2*)bp = pk.u;

    if (l == 0) {
        const float lo = scale >= 0.f ? 1e-6f * scale : -INFINITY;
        const float hi = scale >= 0.f ? INFINITY : 1e-6f * scale;
        W[WS_ZDIAG + n] = fminf(fmaxf(dp * il * ic * scale, lo), hi);
    }
}

// grid (32,16) x 512 threads: 256-row block x 512-col chunk. 8 waves: g = wv>>1 owns
// rows g*64..g*64+63 (rt=0..3); h = wv&1 owns col-half (nt in {2h,2h+1} per 64-slab).
__global__ __launch_bounds__(512, 4) void k2_main(
        const __hip_bfloat16* __restrict__ lastb,
        const __hip_bfloat16* __restrict__ centb,
        const float* __restrict__ wp,
        float* __restrict__ zsum) {
    const int tid  = threadIdx.x;
    const int lane = tid & 63;
    const int wv   = tid >> 6;                // 0..7
    const int g    = wv >> 1;                 // row-group 0..3
    const int h    = wv & 1;                  // col-half 0..1
    const int quad = lane >> 4;
    const int l16  = lane & 15;
    const int R0   = blockIdx.x * 256;
    const int C0   = blockIdx.y * 512;
    const float scale = wp[0] * LOG2E;
    // clamp in exp domain (2^z monotone). scale>=0: e >= c0; scale<0: e <= c0.
    const float c0  = __builtin_amdgcn_exp2f(1e-6f * scale);
    const bool  pos = (scale >= 0.f);

    __shared__ uint4 Bs4[2048];   // 2 x 16 KB double buffer, XOR chunk-swizzled
    char* Bsc = (char*)Bs4;

    // staging: wave wv stages rows wv*8 + i*4 + quad (i=0,1); LDS image = R0 layout
#pragma unroll
    for (int i = 0; i < 2; ++i) {
        const int rr = wv * 8 + i * 4 + quad;
        const int c  = l16 ^ (rr & 15);
        const char* src = (const char*)centb + ((size_t)(C0 + rr) << 8) + (c << 4);
        char* dst = Bsc + (wv * 2048 + i * 1024 + lane * 16);
        __builtin_amdgcn_global_load_lds(
            (const __attribute__((address_space(1))) unsigned int*)src,
            (__attribute__((address_space(3))) unsigned int*)dst, 16, 0, 0);
    }

    // A fragments: rows R0 + g*64 + rt*16 + l16, k = quad*8 + kc*32
    short8 a[4][4];
    {
        const short* ap = (const short*)lastb + (size_t)(R0 + g * 64 + l16) * DEMB + quad * 8;
#pragma unroll
        for (int rt = 0; rt < 4; ++rt)
#pragma unroll
            for (int kc = 0; kc < 4; ++kc)
                a[rt][kc] = *(const short8*)(ap + rt * 16 * DEMB + kc * 32);
    }

    // swizzled B byte offsets within this wave's two ntiles (nt = 2h+j):
    // byte = nt*4096 + l16*256 + ((quad+4kc)^l16)<<4
    int roff[2][4];
#pragma unroll
    for (int j = 0; j < 2; ++j)
#pragma unroll
        for (int kc = 0; kc < 4; ++kc)
            roff[j][kc] = (2 * h + j) * 4096 + l16 * 256 + (((quad + 4 * kc) ^ l16) << 4);

    float racc[4][4] = {{0.f}};

    for (int it = 0; it < 8; ++it) {
        // drains vmcnt -> DMA(it) landed; also all waves done reading buf[(it+1)&1]
        __syncthreads();
        if (it < 7) {
            const int c0n = C0 + (it + 1) * 64;
            char* bufn = Bsc + ((it + 1) & 1) * 16384;
#pragma unroll
            for (int i = 0; i < 2; ++i) {
                const int rr = wv * 8 + i * 4 + quad;
                const int c  = l16 ^ (rr & 15);
                const char* src = (const char*)centb + ((size_t)(c0n + rr) << 8) + (c << 4);
                char* dst = bufn + (wv * 2048 + i * 1024 + lane * 16);
                __builtin_amdgcn_global_load_lds(
                    (const __attribute__((address_space(1))) unsigned int*)src,
                    (__attribute__((address_space(3))) unsigned int*)dst, 16, 0, 0);
            }
        }
        const char* buf = Bsc + (it & 1) * 16384;
#pragma unroll
        for (int j = 0; j < 2; ++j) {
            short8 b[4];
#pragma unroll
            for (int kc = 0; kc < 4; ++kc)
                b[kc] = *(const short8*)(buf + roff[j][kc]);
            if (pos) {   // wave-uniform: single-sided clamp
#pragma unroll
                for (int rt = 0; rt < 4; ++rt) {
                    f32x4 acc = {0.f, 0.f, 0.f, 0.f};
#pragma unroll
                    for (int kc = 0; kc < 4; ++kc)
                        acc = __builtin_amdgcn_mfma_f32_16x16x32_bf16(a[rt][kc], b[kc], acc, 0, 0, 0);
#pragma unroll
                    for (int r = 0; r < 4; ++r)
                        racc[rt][r] += fmaxf(__builtin_amdgcn_exp2f(acc[r]), c0);
                }
            } else {
#pragma unroll
                for (int rt = 0; rt < 4; ++rt) {
                    f32x4 acc = {0.f, 0.f, 0.f, 0.f};
#pragma unroll
                    for (int kc = 0; kc < 4; ++kc)
                        acc = __builtin_amdgcn_mfma_f32_16x16x32_bf16(a[rt][kc], b[kc], acc, 0, 0, 0);
#pragma unroll
                    for (int r = 0; r < 4; ++r)
                        racc[rt][r] += fminf(__builtin_amdgcn_exp2f(acc[r]), c0);
                }
            }
        }
    }
    // reduce row sums over the 16 l16-lanes holding the same rows
#pragma unroll
    for (int off = 1; off < 16; off <<= 1)
#pragma unroll
        for (int rt = 0; rt < 4; ++rt)
#pragma unroll
            for (int r = 0; r < 4; ++r)
                racc[rt][r] += __shfl_xor(racc[rt][r], off);
    if (l16 == 0) {
#pragma unroll
        for (int rt = 0; rt < 4; ++rt)
#pragma unroll
            for (int r = 0; r < 4; ++r)
                atomicAdd(&zsum[R0 + g * 64 + rt * 16 + quad * 4 + r], racc[rt][r]);
    }
}

__global__ __launch_bounds__(256) void k3_loss(const float* __restrict__ W,
                                               float* __restrict__ out) {
    float v = 0.f;
    for (int n = threadIdx.x; n < NSPK; n += 256)
        v += __log2f(W[WS_ZSUM + n]) - W[WS_ZDIAG + n];
#pragma unroll
    for (int off = 1; off < 64; off <<= 1) v += __shfl_xor(v, off);
    __shared__ float red[4];
    if ((threadIdx.x & 63) == 0) red[threadIdx.x >> 6] = v;
    __syncthreads();
    if (threadIdx.x == 0)
        out[0] = (red[0] + red[1] + red[2] + red[3]) * (LN2 / (float)NSPK);
}

extern "C" void kernel_launch(void* const* d_in, const int* in_sizes, int n_in,
                              void* d_out, int out_size, void* d_ws, size_t ws_size,
                              hipStream_t stream) {
    const float* x = (const float*)d_in[0];
    const float* w = (const float*)d_in[1];
    // b (d_in[2]) cancels analytically — unused.
    float* W = (float*)d_ws;
    __hip_bfloat16* lastb = (__hip_bfloat16*)((char*)d_ws + WS_LASTB);
    __hip_bfloat16* centb = (__hip_bfloat16*)((char*)d_ws + WS_CENTB);

    k1_prep<<<NSPK / 4, 256, 0, stream>>>(x, w, W, lastb, centb);
    k2_main<<<dim3(32, 16), 512, 0, stream>>>(lastb, centb, w, W + WS_ZSUM);
    // PROBE: duplicate k2 into scratch zsum2; T6 - T7(next round) = k2 duration.
    k2_main<<<dim3(32, 16), 512, 0, stream>>>(lastb, centb, w, W + WS_ZSUM2);
    k3_loss<<<1, 256, 0, stream>>>(W, (float*)d_out);
}

// Round 7
// 116.499 us; speedup vs baseline: 1.5513x; 1.5513x over previous
//
#include <hip/hip_runtime.h>
#include <hip/hip_bf16.h>

// AngleProtoLoss: loss = -mean_n logsoftmax(clip(cos(last_n,cent_k),1e-6)*w+b)[n,n]
// Identity: loss_n = ln2*(log2(sum_k 2^{z_nk}) - z_nn), z = clamp(cos*w*log2e); b cancels.
// k1: centroids+norms -> unit cent (bf16), w*log2e-prescaled unit last (bf16), fp32 z_nn.
// k2: grid (32,16) x 512 threads (8 waves x 32 rows, a[2][4] = 32 VGPR A in regs).
//     Staged slab DOUBLED to 128 cols/iter (2 x 32 KB LDS double-buffer, 64 KB total,
//     2 blocks/CU): 4 iters instead of 8 -> half the syncthreads+vmcnt(0) drains,
//     2x compute per DMA window. One-sided clamp in exp domain. Same XOR chunk swizzle.
// k3: single block: loss = ln2/N * sum_n (log2(S_n) - z_nn).
// LEDGER: fill 44.5us fixed; non-k2 ~75.3us (k1+k3+restore+gaps); k2_R5 = 35.3us
//     (probe-measured R6); pipe floor ~10-12us -> barrier/drain stall is the target.
// R1: per-block __threadfence()+ticket fusion serializes k2 to 73us. Never again.
// R3+R6: a[4][4] at VGPR=64 configs SPILLS (WRITE 23-170MB scratch). Keep a[2][4].

typedef __attribute__((ext_vector_type(8))) short short8;
typedef __attribute__((ext_vector_type(4))) float f32x4;

#define NSPK 8192
#define DEMB 128
#define MUTT 10
#define LOG2E 1.44269504088896340736f
#define LN2   0.69314718055994530942f

// workspace floats: [0,8192)=zdiag, [8192,16384)=zsum; then bf16 matrices
#define WS_ZDIAG 0
#define WS_ZSUM  8192
#define WS_LASTB 65536      // byte offset, 2 MB
#define WS_CENTB 2162688    // byte offset, 2 MB

__global__ __launch_bounds__(256) void k1_prep(const float* __restrict__ x,
                                               const float* __restrict__ wp,
                                               float* __restrict__ W,
                                               __hip_bfloat16* __restrict__ lastb,
                                               __hip_bfloat16* __restrict__ centb) {
    const int wv = threadIdx.x >> 6;
    const int l  = threadIdx.x & 63;
    const int n  = blockIdx.x * 4 + wv;           // one wave per speaker
    if (blockIdx.x < 32) W[WS_ZSUM + blockIdx.x * 256 + threadIdx.x] = 0.f;

    // flat 1280 floats per speaker; lane l, step i -> float4 at 64*i + l.
    // lanes 0..31: m = 2i ; lanes 32..63: m = 2i+1
    const float4* xr = (const float4*)(x + (size_t)n * (MUTT * DEMB)) + l;
    float4 v[5];
#pragma unroll
    for (int i = 0; i < 5; ++i) v[i] = xr[i * 64];

    float4 cs;
    cs.x = ((v[0].x + v[1].x) + (v[2].x + v[3].x)) + v[4].x;
    cs.y = ((v[0].y + v[1].y) + (v[2].y + v[3].y)) + v[4].y;
    cs.z = ((v[0].z + v[1].z) + (v[2].z + v[3].z)) + v[4].z;
    cs.w = ((v[0].w + v[1].w) + (v[2].w + v[3].w)) + v[4].w;
    cs.x += __shfl_xor(cs.x, 32);
    cs.y += __shfl_xor(cs.y, 32);
    cs.z += __shfl_xor(cs.z, 32);
    cs.w += __shfl_xor(cs.w, 32);
    float4 cent;
    cent.x = cs.x * 0.1f; cent.y = cs.y * 0.1f; cent.z = cs.z * 0.1f; cent.w = cs.w * 0.1f;

    // last row (m=9) lives in v[4] of lanes >= 32; mirror into lanes < 32
    float4 lv = v[4];
    {
        const float tx = __shfl_xor(lv.x, 32);
        const float ty = __shfl_xor(lv.y, 32);
        const float tz = __shfl_xor(lv.z, 32);
        const float tw = __shfl_xor(lv.w, 32);
        if (l < 32) { lv.x = tx; lv.y = ty; lv.z = tz; lv.w = tw; }
    }

    float sl = lv.x * lv.x + lv.y * lv.y + lv.z * lv.z + lv.w * lv.w;
    float sc = cent.x * cent.x + cent.y * cent.y + cent.z * cent.z + cent.w * cent.w;
    float dp = lv.x * cent.x + lv.y * cent.y + lv.z * cent.z + lv.w * cent.w;
#pragma unroll
    for (int off = 1; off < 32; off <<= 1) {
        sl += __shfl_xor(sl, off);
        sc += __shfl_xor(sc, off);
        dp += __shfl_xor(dp, off);
    }
    const float il = rsqrtf(sl), ic = rsqrtf(sc);
    const float scale = wp[0] * LOG2E;
    const float as = il * scale;                  // prescale last by w*log2e

    const float  f  = (l < 32) ? as : ic;
    const float4 s4 = (l < 32) ? lv : cent;
    __hip_bfloat16* bp = ((l < 32) ? lastb : centb) + (size_t)n * DEMB + 4 * (l & 31);
    union { __hip_bfloat162 h[2]; uint2 u; } pk;
    pk.h[0].x = __float2bfloat16(s4.x * f);
    pk.h[0].y = __float2bfloat16(s4.y * f);
    pk.h[1].x = __float2bfloat16(s4.z * f);
    pk.h[1].y = __float2bfloat16(s4.w * f);
    *(uint2*)bp = pk.u;

    if (l == 0) {
        const float lo = scale >= 0.f ? 1e-6f * scale : -INFINITY;
        const float hi = scale >= 0.f ? INFINITY : 1e-6f * scale;
        W[WS_ZDIAG + n] = fminf(fmaxf(dp * il * ic * scale, lo), hi);
    }
}

// grid (32,16) x 512 threads: 256-row block x 512-col chunk. 8 waves; wave owns 32 rows
// (a[2][4], no spill). Slab = 128 B-rows x 128 k = 32 KB per iter, 4 iters, 2x32KB dbuf.
// LDS image: row rr (0..127) at byte rr*256; 16B slot s holds global chunk s ^ (rr&15).
__global__ __launch_bounds__(512, 4) void k2_main(
        const __hip_bfloat16* __restrict__ lastb,
        const __hip_bfloat16* __restrict__ centb,
        const float* __restrict__ wp,
        float* __restrict__ zsum) {
    const int tid  = threadIdx.x;
    const int lane = tid & 63;
    const int wv   = tid >> 6;                // 0..7
    const int quad = lane >> 4;
    const int l16  = lane & 15;
    const int R0   = blockIdx.x * 256;
    const int C0   = blockIdx.y * 512;
    const float scale = wp[0] * LOG2E;
    // clamp in exp domain (2^z monotone). scale>=0: e >= c0; scale<0: e <= c0.
    const float c0  = __builtin_amdgcn_exp2f(1e-6f * scale);
    const bool  pos = (scale >= 0.f);

    __shared__ uint4 Bs4[4096];   // 2 x 32 KB double buffer, XOR chunk-swizzled
    char* Bsc = (char*)Bs4;

    // staging: wave wv stages rows wv*16 + i*4 + quad (i=0..3); 4 x global_load_lds
#pragma unroll
    for (int i = 0; i < 4; ++i) {
        const int rr = wv * 16 + i * 4 + quad;
        const int c  = l16 ^ (rr & 15);
        const char* src = (const char*)centb + ((size_t)(C0 + rr) << 8) + (c << 4);
        char* dst = Bsc + (wv * 4096 + i * 1024 + lane * 16);
        __builtin_amdgcn_global_load_lds(
            (const __attribute__((address_space(1))) unsigned int*)src,
            (__attribute__((address_space(3))) unsigned int*)dst, 16, 0, 0);
    }

    // A fragments (held whole kernel): rows R0 + wv*32 + rt*16 + l16, k = quad*8 + kc*32
    short8 a[2][4];
    {
        const short* ap = (const short*)lastb + (size_t)(R0 + wv * 32 + l16) * DEMB + quad * 8;
#pragma unroll
        for (int rt = 0; rt < 2; ++rt)
#pragma unroll
            for (int kc = 0; kc < 4; ++kc)
                a[rt][kc] = *(const short8*)(ap + rt * 16 * DEMB + kc * 32);
    }

    // swizzled B-fragment byte offsets within a 16-row ntile: row=l16, chunk=(quad+4kc)^l16
    int roff[4];
#pragma unroll
    for (int kc = 0; kc < 4; ++kc)
        roff[kc] = l16 * 256 + (((quad + 4 * kc) ^ l16) << 4);

    float racc[2][4] = {{0.f}};

    for (int it = 0; it < 4; ++it) {
        // drains vmcnt -> DMA(it) landed; also all waves done reading buf[(it+1)&1]
        __syncthreads();
        if (it < 3) {
            const int c0n = C0 + (it + 1) * 128;
            char* bufn = Bsc + ((it + 1) & 1) * 32768;
#pragma unroll
            for (int i = 0; i < 4; ++i) {
                const int rr = wv * 16 + i * 4 + quad;
                const int c  = l16 ^ (rr & 15);
                const char* src = (const char*)centb + ((size_t)(c0n + rr) << 8) + (c << 4);
                char* dst = bufn + (wv * 4096 + i * 1024 + lane * 16);
                __builtin_amdgcn_global_load_lds(
                    (const __attribute__((address_space(1))) unsigned int*)src,
                    (__attribute__((address_space(3))) unsigned int*)dst, 16, 0, 0);
            }
        }
        const char* buf = Bsc + (it & 1) * 32768;
#pragma unroll
        for (int nt = 0; nt < 8; ++nt) {
            short8 b[4];
#pragma unroll
            for (int kc = 0; kc < 4; ++kc)
                b[kc] = *(const short8*)(buf + nt * 4096 + roff[kc]);
            if (pos) {   // wave-uniform: single-sided clamp
#pragma unroll
                for (int rt = 0; rt < 2; ++rt) {
                    f32x4 acc = {0.f, 0.f, 0.f, 0.f};
#pragma unroll
                    for (int kc = 0; kc < 4; ++kc)
                        acc = __builtin_amdgcn_mfma_f32_16x16x32_bf16(a[rt][kc], b[kc], acc, 0, 0, 0);
#pragma unroll
                    for (int r = 0; r < 4; ++r)
                        racc[rt][r] += fmaxf(__builtin_amdgcn_exp2f(acc[r]), c0);
                }
            } else {
#pragma unroll
                for (int rt = 0; rt < 2; ++rt) {
                    f32x4 acc = {0.f, 0.f, 0.f, 0.f};
#pragma unroll
                    for (int kc = 0; kc < 4; ++kc)
                        acc = __builtin_amdgcn_mfma_f32_16x16x32_bf16(a[rt][kc], b[kc], acc, 0, 0, 0);
#pragma unroll
                    for (int r = 0; r < 4; ++r)
                        racc[rt][r] += fminf(__builtin_amdgcn_exp2f(acc[r]), c0);
                }
            }
        }
    }
    // reduce row sums over the 16 l16-lanes holding the same rows
#pragma unroll
    for (int off = 1; off < 16; off <<= 1)
#pragma unroll
        for (int rt = 0; rt < 2; ++rt)
#pragma unroll
            for (int r = 0; r < 4; ++r)
                racc[rt][r] += __shfl_xor(racc[rt][r], off);
    if (l16 == 0) {
#pragma unroll
        for (int rt = 0; rt < 2; ++rt)
#pragma unroll
            for (int r = 0; r < 4; ++r)
                atomicAdd(&zsum[R0 + wv * 32 + rt * 16 + quad * 4 + r], racc[rt][r]);
    }
}

__global__ __launch_bounds__(256) void k3_loss(const float* __restrict__ W,
                                               float* __restrict__ out) {
    float v = 0.f;
    for (int n = threadIdx.x; n < NSPK; n += 256)
        v += __log2f(W[WS_ZSUM + n]) - W[WS_ZDIAG + n];
#pragma unroll
    for (int off = 1; off < 64; off <<= 1) v += __shfl_xor(v, off);
    __shared__ float red[4];
    if ((threadIdx.x & 63) == 0) red[threadIdx.x >> 6] = v;
    __syncthreads();
    if (threadIdx.x == 0)
        out[0] = (red[0] + red[1] + red[2] + red[3]) * (LN2 / (float)NSPK);
}

extern "C" void kernel_launch(void* const* d_in, const int* in_sizes, int n_in,
                              void* d_out, int out_size, void* d_ws, size_t ws_size,
                              hipStream_t stream) {
    const float* x = (const float*)d_in[0];
    const float* w = (const float*)d_in[1];
    // b (d_in[2]) cancels analytically — unused.
    float* W = (float*)d_ws;
    __hip_bfloat16* lastb = (__hip_bfloat16*)((char*)d_ws + WS_LASTB);
    __hip_bfloat16* centb = (__hip_bfloat16*)((char*)d_ws + WS_CENTB);

    k1_prep<<<NSPK / 4, 256, 0, stream>>>(x, w, W, lastb, centb);
    k2_main<<<dim3(32, 16), 512, 0, stream>>>(lastb, centb, w, W + WS_ZSUM);
    k3_loss<<<1, 256, 0, stream>>>(W, (float*)d_out);
}